// Round 14
// baseline (124.701 us; speedup 1.0000x reference)
//
#include <hip/hip_runtime.h>

// Causal attention, fp32 in/out, B=8 S=2048 D=64, NO 1/sqrt(d) scaling.
// R14: SINGLE DISPATCH — prep eliminated by converting inline per block
// (no cross-block data deps, no grid sync; R6 coop + R8 barrier both died).
// Ledger: 2 dispatches cost ~60us fixed overhead vs ~35 for 1.
//  - Q,K: fp32 loaded directly (same bytes as Kh+Kl), truncation hi/lo split
//    in registers (~4 VALU/val; residual capture => error ~2^-16, negligible).
//  - V: per-chain 32x64 LDS transpose per wave: swizzled conflict-free
//    writes (bank = 8*(l&3) + (l>>3), exact 2-way), stride-40-ushort rows
//    (80B, 16B-aligned) so fragment reads are aligned b128.
// Body = R10 (best: 47.4us): 512x256, gp-pair K loads, triangle halves,
// DPP softmax, per-wave sP. Footprint kept small (R12/R13: VGPR>140 regresses).
// Fragment layouts (verified R2):
//   A[m][k]: m=lane&15, k=quad*8+j | B[k][n]: n=lane&15, k=quad*8+j
//   C/D:     col=lane&15, row=quad*4+reg

#define BATCH 8
#define SEQ 2048
#define DIM 64
#define SVT_S 40   // sVt row stride in ushorts (80 B, 16B-aligned reads)

typedef __attribute__((ext_vector_type(8))) short short8;
typedef __attribute__((ext_vector_type(4))) float f32x4;

#define MFMA(a, b, c) __builtin_amdgcn_mfma_f32_16x16x32_bf16(a, b, c, 0, 0, 0)

__device__ __forceinline__ unsigned short f2bf(float x) {   // RNE (for P, V)
    unsigned u = __float_as_uint(x);
    unsigned r = u + 0x7fffu + ((u >> 16) & 1u);
    return (unsigned short)(r >> 16);
}
__device__ __forceinline__ short8 ld8(const unsigned short* p) {
    return *(const short8*)p;
}
// truncation hi/lo split: hi = upper16(x); lo = trunc16(x - hi). Residual
// capture makes total representation error ~|x|*2^-16.
__device__ __forceinline__ void splitA(float4 a, float4 b, short8& h8, short8& l8) {
    float v[8] = {a.x, a.y, a.z, a.w, b.x, b.y, b.z, b.w};
#pragma unroll
    for (int i = 0; i < 8; ++i) {
        unsigned u  = __float_as_uint(v[i]);
        unsigned hu = u & 0xffff0000u;
        h8[i] = (short)(hu >> 16);
        float lf = v[i] - __uint_as_float(hu);
        l8[i] = (short)(__float_as_uint(lf) >> 16);
    }
}

__device__ __forceinline__ float dpp_max16(float x) {
    float o;
    o = __int_as_float(__builtin_amdgcn_update_dpp(0, __float_as_int(x), 0xB1, 0xF, 0xF, true));
    x = fmaxf(x, o);
    o = __int_as_float(__builtin_amdgcn_update_dpp(0, __float_as_int(x), 0x4E, 0xF, 0xF, true));
    x = fmaxf(x, o);
    o = __int_as_float(__builtin_amdgcn_update_dpp(0, __float_as_int(x), 0x141, 0xF, 0xF, true));
    x = fmaxf(x, o);
    o = __int_as_float(__builtin_amdgcn_update_dpp(0, __float_as_int(x), 0x140, 0xF, 0xF, true));
    return fmaxf(x, o);
}
__device__ __forceinline__ float dpp_sum16(float x) {
    float o;
    o = __int_as_float(__builtin_amdgcn_update_dpp(0, __float_as_int(x), 0xB1, 0xF, 0xF, true));
    x += o;
    o = __int_as_float(__builtin_amdgcn_update_dpp(0, __float_as_int(x), 0x4E, 0xF, 0xF, true));
    x += o;
    o = __int_as_float(__builtin_amdgcn_update_dpp(0, __float_as_int(x), 0x141, 0xF, 0xF, true));
    x += o;
    o = __int_as_float(__builtin_amdgcn_update_dpp(0, __float_as_int(x), 0x140, 0xF, 0xF, true));
    return x + o;
}

// ---- single fused kernel: 512 blocks x 256 threads ----
__global__ __launch_bounds__(256) void attn_fused(
    const float* __restrict__ Q, const float* __restrict__ K,
    const float* __restrict__ V, float* __restrict__ O)
{
    // per-wave: sP (ushort[16][136]) == sO (float[16][68]) = 4352 B (union)
    //           sVt (ushort[64][SVT_S]) = 5120 B (V chain transpose)
    __shared__ __align__(16) char scratch[4][4352];
    __shared__ __align__(16) unsigned short sVt[4][64 * SVT_S];
    __shared__ float sMl[4][16][2];

    const int bid  = blockIdx.x;
    const int b    = bid & (BATCH - 1);
    const int pair = bid >> 3;              // 0..63

    const int t    = threadIdx.x;
    const int w    = t >> 6;
    const int lane = t & 63;
    const int quad = lane >> 4;
    const int n16  = lane & 15;
    const int boff = b * SEQ;

    unsigned short* sPw  = (unsigned short*)scratch[w];   // [16][136]
    float*          sOw  = (float*)scratch[w];            // [16][68]
    unsigned short* sVtw = sVt[w];                        // [64][SVT_S]

    for (int half = 0; half < 2; ++half) {
        const int qt = half ? (127 - pair) : pair;
        const int q0 = qt * 16;
        const int q_max = q0 + 15;

        // ---- Q fragments: inline fp32 -> hi/lo split ----
        short8 qh0, ql0, qh1, ql1;
        {
            const float* qb = Q + ((size_t)(boff + q0 + n16)) * DIM + quad * 8;
            splitA(*(const float4*)(qb),      *(const float4*)(qb + 4),  qh0, ql0);
            splitA(*(const float4*)(qb + 32), *(const float4*)(qb + 36), qh1, ql1);
        }

        float m0 = -1e30f, m1 = -1e30f, m2 = -1e30f, m3 = -1e30f;
        float l0 = 0.f, l1 = 0.f, l2 = 0.f, l3 = 0.f;
        f32x4 oacc[4];
#pragma unroll
        for (int i = 0; i < 4; ++i) oacc[i] = (f32x4){0.f, 0.f, 0.f, 0.f};

        for (int kb = w * 128; kb <= q_max; kb += 512) {
            const int rem  = q_max - kb;
            const int nsub = min(8, (rem >> 4) + 1);
            const int nchain = (nsub + 1) >> 1;
            f32x4 sacc[8];

            // ---- QK^T: gp-pairs; fp32 K loaded + split inline ----
#pragma unroll
            for (int gp = 0; gp < 4; ++gp) {
                const int stA = 2 * gp, stB = stA + 1;
                if (stA < nsub) {
                    const float* kpA = K + (size_t)(boff + kb + stA * 16 + n16) * DIM + quad * 8;
                    float4 a0 = *(const float4*)(kpA),      a1 = *(const float4*)(kpA + 4);
                    float4 a2 = *(const float4*)(kpA + 32), a3 = *(const float4*)(kpA + 36);
                    const bool okB = (stB < nsub);
                    float4 b0, b1, b2, b3;
                    if (okB) {
                        const float* kpB = K + (size_t)(boff + kb + stB * 16 + n16) * DIM + quad * 8;
                        b0 = *(const float4*)(kpB);      b1 = *(const float4*)(kpB + 4);
                        b2 = *(const float4*)(kpB + 32); b3 = *(const float4*)(kpB + 36);
                    }
                    short8 kh0, kl0, kh1, kl1;
                    splitA(a0, a1, kh0, kl0);
                    splitA(a2, a3, kh1, kl1);
                    f32x4 acc = (f32x4){0.f, 0.f, 0.f, 0.f};
                    acc = MFMA(qh0, kh0, acc);
                    acc = MFMA(qh1, kh1, acc);
                    acc = MFMA(qh0, kl0, acc);
                    acc = MFMA(qh1, kl1, acc);
                    acc = MFMA(ql0, kh0, acc);
                    acc = MFMA(ql1, kh1, acc);
                    sacc[stA] = acc;
                    if (okB) {
                        splitA(b0, b1, kh0, kl0);
                        splitA(b2, b3, kh1, kl1);
                        f32x4 accB = (f32x4){0.f, 0.f, 0.f, 0.f};
                        accB = MFMA(qh0, kh0, accB);
                        accB = MFMA(qh1, kh1, accB);
                        accB = MFMA(qh0, kl0, accB);
                        accB = MFMA(qh1, kl1, accB);
                        accB = MFMA(ql0, kh0, accB);
                        accB = MFMA(ql1, kh1, accB);
                        sacc[stB] = accB;
                    } else {
                        sacc[stB] = (f32x4){-1e30f, -1e30f, -1e30f, -1e30f};
                    }
                } else {
                    sacc[stA] = (f32x4){-1e30f, -1e30f, -1e30f, -1e30f};
                    sacc[stB] = (f32x4){-1e30f, -1e30f, -1e30f, -1e30f};
                }
            }

            // ---- causal mask ----
            if (kb + 127 > q0) {
#pragma unroll
                for (int st = 0; st < 8; ++st) {
                    if (st < nsub) {
                        const int key = kb + st * 16 + n16;
#pragma unroll
                        for (int r = 0; r < 4; ++r)
                            if (key > q0 + quad * 4 + r) sacc[st][r] = -1e30f;
                    }
                }
            }

            // ---- online softmax over 128 keys (DPP) ----
            float mt0 = sacc[0][0], mt1 = sacc[0][1], mt2 = sacc[0][2], mt3 = sacc[0][3];
#pragma unroll
            for (int st = 1; st < 8; ++st) {
                mt0 = fmaxf(mt0, sacc[st][0]);
                mt1 = fmaxf(mt1, sacc[st][1]);
                mt2 = fmaxf(mt2, sacc[st][2]);
                mt3 = fmaxf(mt3, sacc[st][3]);
            }
            mt0 = dpp_max16(mt0); mt1 = dpp_max16(mt1);
            mt2 = dpp_max16(mt2); mt3 = dpp_max16(mt3);
            const float mn0 = fmaxf(m0, mt0), mn1 = fmaxf(m1, mt1);
            const float mn2 = fmaxf(m2, mt2), mn3 = fmaxf(m3, mt3);
            const float a0 = __expf(m0 - mn0), a1 = __expf(m1 - mn1);
            const float a2 = __expf(m2 - mn2), a3 = __expf(m3 - mn3);
            m0 = mn0; m1 = mn1; m2 = mn2; m3 = mn3;

            float ps0 = 0.f, ps1 = 0.f, ps2 = 0.f, ps3 = 0.f;
            const int stmax = 2 * nchain;
#pragma unroll
            for (int st = 0; st < 8; ++st) {
                if (st < stmax) {
                    float p0 = 0.f, p1 = 0.f, p2 = 0.f, p3 = 0.f;
                    if (st < nsub) {
                        p0 = __expf(sacc[st][0] - mn0);
                        p1 = __expf(sacc[st][1] - mn1);
                        p2 = __expf(sacc[st][2] - mn2);
                        p3 = __expf(sacc[st][3] - mn3);
                        ps0 += p0; ps1 += p1; ps2 += p2; ps3 += p3;
                    }
                    const int col = st * 16 + n16;
                    sPw[(quad * 4 + 0) * 136 + col] = f2bf(p0);
                    sPw[(quad * 4 + 1) * 136 + col] = f2bf(p1);
                    sPw[(quad * 4 + 2) * 136 + col] = f2bf(p2);
                    sPw[(quad * 4 + 3) * 136 + col] = f2bf(p3);
                }
            }
            ps0 = dpp_sum16(ps0); ps1 = dpp_sum16(ps1);
            ps2 = dpp_sum16(ps2); ps3 = dpp_sum16(ps3);
            l0 = l0 * a0 + ps0; l1 = l1 * a1 + ps1;
            l2 = l2 * a2 + ps2; l3 = l3 * a3 + ps3;
#pragma unroll
            for (int nt = 0; nt < 4; ++nt) {
                oacc[nt][0] *= a0; oacc[nt][1] *= a1;
                oacc[nt][2] *= a2; oacc[nt][3] *= a3;
            }

            // ---- PV: per 32-key chain, stage V via per-wave LDS transpose ----
            // (safe: kb <= 1920 and nchain <= 4 => V rows <= 2047)
#pragma unroll
            for (int ch = 0; ch < 4; ++ch) {
                if (ch < nchain) {
                    const int kv0 = kb + ch * 32;
                    // swizzled conflict-free staging: bank = 8*(l&3)+(l>>3)
#pragma unroll
                    for (int i = 0; i < 8; ++i) {
                        const int c = (lane & 3) + 4 * (i & 3);   // dim group (0..15)
                        const int r = (lane >> 2) + 16 * (i >> 2); // key (0..31)
                        float4 v = *(const float4*)(V + ((size_t)(boff + kv0 + r)) * DIM + c * 4);
                        sVtw[(c * 4 + 0) * SVT_S + r] = f2bf(v.x);
                        sVtw[(c * 4 + 1) * SVT_S + r] = f2bf(v.y);
                        sVtw[(c * 4 + 2) * SVT_S + r] = f2bf(v.z);
                        sVtw[(c * 4 + 3) * SVT_S + r] = f2bf(v.w);
                    }
                    short8 pa = ld8(&sPw[n16 * 136 + ch * 32 + quad * 8]);
#pragma unroll
                    for (int nt = 0; nt < 4; ++nt) {
                        short8 vv = ld8(&sVtw[(nt * 16 + n16) * SVT_S + quad * 8]);
                        oacc[nt] = MFMA(pa, vv, oacc[nt]);
                    }
                }
            }
        }

        // ---- flash-combine the 4 waves' partials (sO overlays sP) ----
#pragma unroll
        for (int nt = 0; nt < 4; ++nt)
#pragma unroll
            for (int r = 0; r < 4; ++r)
                sOw[(quad * 4 + r) * 68 + nt * 16 + n16] = oacc[nt][r];
        if (n16 == 0) {
            sMl[w][quad * 4 + 0][0] = m0; sMl[w][quad * 4 + 0][1] = l0;
            sMl[w][quad * 4 + 1][0] = m1; sMl[w][quad * 4 + 1][1] = l1;
            sMl[w][quad * 4 + 2][0] = m2; sMl[w][quad * 4 + 2][1] = l2;
            sMl[w][quad * 4 + 3][0] = m3; sMl[w][quad * 4 + 3][1] = l3;
        }
        __syncthreads();

        const int row  = t >> 4;
        const int col4 = (t & 15) * 4;
        float M = fmaxf(fmaxf(sMl[0][row][0], sMl[1][row][0]),
                        fmaxf(sMl[2][row][0], sMl[3][row][0]));
        float L = 0.f;
        float ox = 0.f, oy = 0.f, oz = 0.f, ow = 0.f;
#pragma unroll
        for (int wv = 0; wv < 4; ++wv) {
            const float ew = __expf(sMl[wv][row][0] - M);
            L += ew * sMl[wv][row][1];
            const float* op = (const float*)scratch[wv] + row * 68 + col4;
            ox += ew * op[0]; oy += ew * op[1]; oz += ew * op[2]; ow += ew * op[3];
        }
        const float inv = 1.0f / L;
        float4 res = make_float4(ox * inv, oy * inv, oz * inv, ow * inv);
        *(float4*)(O + ((size_t)(boff + q0 + row)) * DIM + col4) = res;

        __syncthreads();   // scratch reused as sP by the next half
    }
}

extern "C" void kernel_launch(void* const* d_in, const int* in_sizes, int n_in,
                              void* d_out, int out_size, void* d_ws, size_t ws_size,
                              hipStream_t stream) {
    const float* q = (const float*)d_in[0];
    const float* k = (const float*)d_in[1];
    const float* v = (const float*)d_in[2];
    float* out = (float*)d_out;
    (void)d_ws; (void)ws_size;   // no workspace needed — single fused kernel

    attn_fused<<<dim3(512), dim3(256), 0, stream>>>(q, k, v, out);
}

// Round 15
// 108.807 us; speedup vs baseline: 1.1461x; 1.1461x over previous
//
#include <hip/hip_runtime.h>

// Causal attention, fp32 in/out, B=8 S=2048 D=64, NO 1/sqrt(d) scaling.
// R15 = R10 (best: attn_main 47.4us, total 112.5) consolidated:
//  - Q converted INLINE via truncation hi/lo split (R14-verified: absmax
//    unchanged at 0.03125) -> Qh/Ql arrays gone, prep's Q work gone.
//  - prep slimmed: K convert (1024 blks) + V fragment-major (256 blks).
// Main loop untouched from R10 (R12/R13/R14: any footprint/structure change
// regressed; only transaction-count reduction ever helped).
// Ledger: ~50us of total is fixed harness cost (R14 single-dispatch proof);
// kernel floor ~12us traffic + latency exposure.
// Fragment layouts (verified R2):
//   A[m][k]: m=lane&15, k=quad*8+j | B[k][n]: n=lane&15, k=quad*8+j
//   C/D:     col=lane&15, row=quad*4+reg
// Vf layout: chunk c(32 keys), dim-group nt: lane l holds
//   V[b][c*32+(l>>4)*8+j][nt*16+(l&15)], j=0..7 (16B, consecutive by lane).

#define BATCH 8
#define SEQ 2048
#define DIM 64
#define NEL (BATCH * SEQ * DIM)

typedef __attribute__((ext_vector_type(8))) short short8;
typedef __attribute__((ext_vector_type(4))) float f32x4;

#define MFMA(a, b, c) __builtin_amdgcn_mfma_f32_16x16x32_bf16(a, b, c, 0, 0, 0)

__device__ __forceinline__ unsigned short f2bf(float x) {   // RNE
    unsigned u = __float_as_uint(x);
    unsigned r = u + 0x7fffu + ((u >> 16) & 1u);
    return (unsigned short)(r >> 16);
}
__device__ __forceinline__ float bf2f(unsigned short h) {
    return __uint_as_float(((unsigned)h) << 16);
}
__device__ __forceinline__ short8 ld8(const unsigned short* p) {
    return *(const short8*)p;
}
// truncation hi/lo split (R14-verified): hi = upper16(x); lo = trunc16(x-hi).
__device__ __forceinline__ void splitA(float4 a, float4 b, short8& h8, short8& l8) {
    float v[8] = {a.x, a.y, a.z, a.w, b.x, b.y, b.z, b.w};
#pragma unroll
    for (int i = 0; i < 8; ++i) {
        unsigned u  = __float_as_uint(v[i]);
        unsigned hu = u & 0xffff0000u;
        h8[i] = (short)(hu >> 16);
        float lf = v[i] - __uint_as_float(hu);
        l8[i] = (short)(__float_as_uint(lf) >> 16);
    }
}

__device__ __forceinline__ float dpp_max16(float x) {
    float o;
    o = __int_as_float(__builtin_amdgcn_update_dpp(0, __float_as_int(x), 0xB1, 0xF, 0xF, true));
    x = fmaxf(x, o);
    o = __int_as_float(__builtin_amdgcn_update_dpp(0, __float_as_int(x), 0x4E, 0xF, 0xF, true));
    x = fmaxf(x, o);
    o = __int_as_float(__builtin_amdgcn_update_dpp(0, __float_as_int(x), 0x141, 0xF, 0xF, true));
    x = fmaxf(x, o);
    o = __int_as_float(__builtin_amdgcn_update_dpp(0, __float_as_int(x), 0x140, 0xF, 0xF, true));
    return fmaxf(x, o);
}
__device__ __forceinline__ float dpp_sum16(float x) {
    float o;
    o = __int_as_float(__builtin_amdgcn_update_dpp(0, __float_as_int(x), 0xB1, 0xF, 0xF, true));
    x += o;
    o = __int_as_float(__builtin_amdgcn_update_dpp(0, __float_as_int(x), 0x4E, 0xF, 0xF, true));
    x += o;
    o = __int_as_float(__builtin_amdgcn_update_dpp(0, __float_as_int(x), 0x141, 0xF, 0xF, true));
    x += o;
    o = __int_as_float(__builtin_amdgcn_update_dpp(0, __float_as_int(x), 0x140, 0xF, 0xF, true));
    return x + o;
}

// ---- pre-pass: K hi-lo split convert (blk<1024) + V fragment-major ----
__global__ __launch_bounds__(256) void prep(
    const float* __restrict__ K, const float* __restrict__ V,
    unsigned short* __restrict__ Kh, unsigned short* __restrict__ Kl,
    unsigned short* __restrict__ Vf)
{
    __shared__ unsigned short sT[64][72];   // [dim][key] for one 64-key tile
    const int blk = blockIdx.x;
    const int t = threadIdx.x;

    if (blk < 1024) {
        const int off = (blk * 256 + t) * 4;    // covers NEL exactly
        float4 v = *(const float4*)(K + off);
        ushort4 h, l;
        h.x = f2bf(v.x); l.x = f2bf(v.x - bf2f(h.x));
        h.y = f2bf(v.y); l.y = f2bf(v.y - bf2f(h.y));
        h.z = f2bf(v.z); l.z = f2bf(v.z - bf2f(h.z));
        h.w = f2bf(v.w); l.w = f2bf(v.w - bf2f(h.w));
        *(ushort4*)(Kh + off) = h;
        *(ushort4*)(Kl + off) = l;
        return;
    }

    const int tile = blk - 1024;            // 8 batches * 32 tiles of 64 keys
    const int b = tile >> 5;
    const int s0 = (tile & 31) * 64;
    const int srow = t >> 4;
    const int d4   = (t & 15) * 4;
#pragma unroll
    for (int i = 0; i < 4; ++i) {
        const int row = srow + i * 16;
        float4 v = *(const float4*)(V + ((size_t)(b * SEQ + s0 + row)) * DIM + d4);
        sT[d4 + 0][row] = f2bf(v.x);
        sT[d4 + 1][row] = f2bf(v.y);
        sT[d4 + 2][row] = f2bf(v.z);
        sT[d4 + 3][row] = f2bf(v.w);
    }
    __syncthreads();
#pragma unroll
    for (int i = 0; i < 2; ++i) {
        const int fid = t + i * 256;
        const int cc  = fid >> 8;
        const int nt  = (fid >> 6) & 3;
        const int l   = fid & 63;
        const int key = cc * 32 + (l >> 4) * 8;
        const int dim = nt * 16 + (l & 15);
        const int c   = (s0 >> 5) + cc;
        unsigned short* dst =
            Vf + ((((size_t)(b * 64 + c)) * 4 + nt) << 9) + l * 8;
        *(float4*)dst = *(const float4*)&sT[dim][key];
    }
}

// ---- main: 512 blocks x 256 threads (4 waves), q-tiles {pair, 127-pair} ----
__global__ __launch_bounds__(256) void attn_main(
    const float* __restrict__ Q,
    const unsigned short* __restrict__ Kh, const unsigned short* __restrict__ Kl,
    const unsigned short* __restrict__ Vf, float* __restrict__ O)
{
    // per-wave union scratch: sP (ushort[16][136]) == sO (float[16][68]) = 4352B
    __shared__ __align__(16) char scratch[4][4352];
    __shared__ float sMl[4][16][2];

    const int bid  = blockIdx.x;
    const int b    = bid & (BATCH - 1);
    const int pair = bid >> 3;              // 0..63

    const int t    = threadIdx.x;
    const int w    = t >> 6;
    const int lane = t & 63;
    const int quad = lane >> 4;
    const int n16  = lane & 15;
    const int boff = b * SEQ;

    unsigned short* sPw = (unsigned short*)scratch[w];   // [16][136]
    float*          sOw = (float*)scratch[w];            // [16][68]

    for (int half = 0; half < 2; ++half) {
        const int qt = half ? (127 - pair) : pair;
        const int q0 = qt * 16;
        const int q_max = q0 + 15;

        // ---- Q fragments: inline fp32 -> hi/lo truncation split ----
        short8 qh0, ql0, qh1, ql1;
        {
            const float* qb = Q + ((size_t)(boff + q0 + n16)) * DIM + quad * 8;
            splitA(*(const float4*)(qb),      *(const float4*)(qb + 4),  qh0, ql0);
            splitA(*(const float4*)(qb + 32), *(const float4*)(qb + 36), qh1, ql1);
        }

        float m0 = -1e30f, m1 = -1e30f, m2 = -1e30f, m3 = -1e30f;
        float l0 = 0.f, l1 = 0.f, l2 = 0.f, l3 = 0.f;
        f32x4 oacc[4];
#pragma unroll
        for (int i = 0; i < 4; ++i) oacc[i] = (f32x4){0.f, 0.f, 0.f, 0.f};

        for (int kb = w * 128; kb <= q_max; kb += 512) {
            const int rem  = q_max - kb;
            const int nsub = min(8, (rem >> 4) + 1);
            const int nchain = (nsub + 1) >> 1;
            f32x4 sacc[8];

            // ---- QK^T: 8 subtiles in pairs (16 loads in flight) ----
#pragma unroll
            for (int gp = 0; gp < 4; ++gp) {
                const int stA = 2 * gp, stB = stA + 1;
                if (stA < nsub) {
                    const size_t krA = (size_t)(boff + kb + stA * 16 + n16) * DIM + quad * 8;
                    short8 khA0 = ld8(Kh + krA), khA1 = ld8(Kh + krA + 32);
                    short8 klA0 = ld8(Kl + krA), klA1 = ld8(Kl + krA + 32);
                    const bool okB = (stB < nsub);
                    const size_t krB = (size_t)(boff + kb + stB * 16 + n16) * DIM + quad * 8;
                    short8 khB0, khB1, klB0, klB1;
                    if (okB) {
                        khB0 = ld8(Kh + krB); khB1 = ld8(Kh + krB + 32);
                        klB0 = ld8(Kl + krB); klB1 = ld8(Kl + krB + 32);
                    }
                    f32x4 accA = (f32x4){0.f, 0.f, 0.f, 0.f};
                    accA = MFMA(qh0, khA0, accA);
                    accA = MFMA(qh1, khA1, accA);
                    accA = MFMA(qh0, klA0, accA);
                    accA = MFMA(qh1, klA1, accA);
                    accA = MFMA(ql0, khA0, accA);
                    accA = MFMA(ql1, khA1, accA);
                    sacc[stA] = accA;
                    if (okB) {
                        f32x4 accB = (f32x4){0.f, 0.f, 0.f, 0.f};
                        accB = MFMA(qh0, khB0, accB);
                        accB = MFMA(qh1, khB1, accB);
                        accB = MFMA(qh0, klB0, accB);
                        accB = MFMA(qh1, klB1, accB);
                        accB = MFMA(ql0, khB0, accB);
                        accB = MFMA(ql1, khB1, accB);
                        sacc[stB] = accB;
                    } else {
                        sacc[stB] = (f32x4){-1e30f, -1e30f, -1e30f, -1e30f};
                    }
                } else {
                    sacc[stA] = (f32x4){-1e30f, -1e30f, -1e30f, -1e30f};
                    sacc[stB] = (f32x4){-1e30f, -1e30f, -1e30f, -1e30f};
                }
            }

            // ---- causal mask: any chunk overlapping any query row ----
            if (kb + 127 > q0) {
#pragma unroll
                for (int st = 0; st < 8; ++st) {
                    if (st < nsub) {
                        const int key = kb + st * 16 + n16;
#pragma unroll
                        for (int r = 0; r < 4; ++r)
                            if (key > q0 + quad * 4 + r) sacc[st][r] = -1e30f;
                    }
                }
            }

            // ---- online softmax over 128 keys (DPP reductions) ----
            float mt0 = sacc[0][0], mt1 = sacc[0][1], mt2 = sacc[0][2], mt3 = sacc[0][3];
#pragma unroll
            for (int st = 1; st < 8; ++st) {
                mt0 = fmaxf(mt0, sacc[st][0]);
                mt1 = fmaxf(mt1, sacc[st][1]);
                mt2 = fmaxf(mt2, sacc[st][2]);
                mt3 = fmaxf(mt3, sacc[st][3]);
            }
            mt0 = dpp_max16(mt0); mt1 = dpp_max16(mt1);
            mt2 = dpp_max16(mt2); mt3 = dpp_max16(mt3);
            const float mn0 = fmaxf(m0, mt0), mn1 = fmaxf(m1, mt1);
            const float mn2 = fmaxf(m2, mt2), mn3 = fmaxf(m3, mt3);
            const float a0 = __expf(m0 - mn0), a1 = __expf(m1 - mn1);
            const float a2 = __expf(m2 - mn2), a3 = __expf(m3 - mn3);
            m0 = mn0; m1 = mn1; m2 = mn2; m3 = mn3;

            float ps0 = 0.f, ps1 = 0.f, ps2 = 0.f, ps3 = 0.f;
            const int stmax = 2 * nchain;
#pragma unroll
            for (int st = 0; st < 8; ++st) {
                if (st < stmax) {
                    float p0 = 0.f, p1 = 0.f, p2 = 0.f, p3 = 0.f;
                    if (st < nsub) {
                        p0 = __expf(sacc[st][0] - mn0);
                        p1 = __expf(sacc[st][1] - mn1);
                        p2 = __expf(sacc[st][2] - mn2);
                        p3 = __expf(sacc[st][3] - mn3);
                        ps0 += p0; ps1 += p1; ps2 += p2; ps3 += p3;
                    }
                    const int col = st * 16 + n16;
                    sPw[(quad * 4 + 0) * 136 + col] = f2bf(p0);
                    sPw[(quad * 4 + 1) * 136 + col] = f2bf(p1);
                    sPw[(quad * 4 + 2) * 136 + col] = f2bf(p2);
                    sPw[(quad * 4 + 3) * 136 + col] = f2bf(p3);
                }
            }
            ps0 = dpp_sum16(ps0); ps1 = dpp_sum16(ps1);
            ps2 = dpp_sum16(ps2); ps3 = dpp_sum16(ps3);
            l0 = l0 * a0 + ps0; l1 = l1 * a1 + ps1;
            l2 = l2 * a2 + ps2; l3 = l3 * a3 + ps3;
#pragma unroll
            for (int nt = 0; nt < 4; ++nt) {
                oacc[nt][0] *= a0; oacc[nt][1] *= a1;
                oacc[nt][2] *= a2; oacc[nt][3] *= a3;
            }

            // ---- PV: P from same-wave LDS; V via dense fragment-major loads ----
#pragma unroll
            for (int ch = 0; ch < 4; ++ch) {
                if (ch < nchain) {
                    short8 pa = ld8(&sPw[n16 * 136 + ch * 32 + quad * 8]);
                    const size_t cbase =
                        (((size_t)(b * 64 + (kb >> 5) + ch)) * 4) << 9;
#pragma unroll
                    for (int nt = 0; nt < 4; ++nt) {
                        short8 vv = ld8(Vf + cbase + (nt << 9) + lane * 8);
                        oacc[nt] = MFMA(pa, vv, oacc[nt]);
                    }
                }
            }
        }

        // ---- flash-combine the 4 waves' partials (sO overlays sP) ----
#pragma unroll
        for (int nt = 0; nt < 4; ++nt)
#pragma unroll
            for (int r = 0; r < 4; ++r)
                sOw[(quad * 4 + r) * 68 + nt * 16 + n16] = oacc[nt][r];
        if (n16 == 0) {
            sMl[w][quad * 4 + 0][0] = m0; sMl[w][quad * 4 + 0][1] = l0;
            sMl[w][quad * 4 + 1][0] = m1; sMl[w][quad * 4 + 1][1] = l1;
            sMl[w][quad * 4 + 2][0] = m2; sMl[w][quad * 4 + 2][1] = l2;
            sMl[w][quad * 4 + 3][0] = m3; sMl[w][quad * 4 + 3][1] = l3;
        }
        __syncthreads();

        const int row  = t >> 4;
        const int col4 = (t & 15) * 4;
        float M = fmaxf(fmaxf(sMl[0][row][0], sMl[1][row][0]),
                        fmaxf(sMl[2][row][0], sMl[3][row][0]));
        float L = 0.f;
        float ox = 0.f, oy = 0.f, oz = 0.f, ow = 0.f;
#pragma unroll
        for (int wv = 0; wv < 4; ++wv) {
            const float ew = __expf(sMl[wv][row][0] - M);
            L += ew * sMl[wv][row][1];
            const float* op = (const float*)scratch[wv] + row * 68 + col4;
            ox += ew * op[0]; oy += ew * op[1]; oz += ew * op[2]; ow += ew * op[3];
        }
        const float inv = 1.0f / L;
        float4 res = make_float4(ox * inv, oy * inv, oz * inv, ow * inv);
        *(float4*)(O + ((size_t)(boff + q0 + row)) * DIM + col4) = res;

        __syncthreads();   // scratch reused as sP by the next half
    }
}

extern "C" void kernel_launch(void* const* d_in, const int* in_sizes, int n_in,
                              void* d_out, int out_size, void* d_ws, size_t ws_size,
                              hipStream_t stream) {
    const float* q = (const float*)d_in[0];
    const float* k = (const float*)d_in[1];
    const float* v = (const float*)d_in[2];
    float* out = (float*)d_out;

    unsigned short* Kh = (unsigned short*)d_ws;
    unsigned short* Kl = Kh + NEL;
    unsigned short* Vf = Kl + NEL;   // 6 MB total in d_ws

    prep<<<dim3(1024 + 256), dim3(256), 0, stream>>>(k, v, Kh, Kl, Vf);
    attn_main<<<dim3(512), dim3(256), 0, stream>>>(q, Kh, Kl, Vf, out);
}